// Round 10
// baseline (220.275 us; speedup 1.0000x reference)
//
#include <hip/hip_runtime.h>
#include <cstdint>
#include <cstddef>

#define BB   4
#define CIN  64
#define VV   50000
#define COUT 128
#define NV   16            // vertices per tile (VV/NV = 3125 exact)
#define NTILES 3125
#define KTOT 448           // CIN*7, kk = k*64 + c
#define KT   14            // KTOT/32 MFMA k-steps
#define PITCH 456          // G LDS row pitch in fp16 elems (448+8)

typedef __attribute__((ext_vector_type(8))) short     short8;
typedef __attribute__((ext_vector_type(8))) _Float16  half8;
typedef __attribute__((ext_vector_type(4))) _Float16  half4;
typedef __attribute__((ext_vector_type(4))) float     f32x4;

// Static device buffers (no ws_size dependence). Rewritten every launch.
__device__ _Float16       g_xt[(size_t)BB * VV * CIN];   // x transposed [b][v][c], fp16, 25.6 MB
__device__ unsigned short g_wb[KT * 8 * 64 * 8];         // W in MFMA A-frag order (fp16 bits), 114 KB

__device__ inline unsigned short f2h(float f) {
    union { _Float16 h; unsigned short u; } cv;
    cv.h = (_Float16)f;
    return cv.u;
}

// ---------------------------------------------------------------------------
// Transpose x[B][C][V] (fp32) -> g_xt[B][V][C] (fp16), with the W pack fused
// into the first 28 blocks of batch 0.
// ---------------------------------------------------------------------------
__global__ __launch_bounds__(256) void transpose_k(const float* __restrict__ x,
                                                   const float* __restrict__ W) {
    if (blockIdx.y == 0 && blockIdx.x < (KT * 8 * 64 + 255) / 256) {
        int idx = blockIdx.x * 256 + threadIdx.x;   // over KT*8*64 = 7168
        if (idx < KT * 8 * 64) {
            int lane = idx & 63;
            int mt   = (idx >> 6) & 7;
            int kt   = idx >> 9;
            int m    = mt * 16 + (lane & 15);
            int kb   = kt * 32 + (lane >> 4) * 8;
            union { unsigned short s[8]; short8 v; } u;
#pragma unroll
            for (int j = 0; j < 8; j++) {
                int kk = kb + j;
                int c  = kk & 63;
                int k  = kk >> 6;
                u.s[j] = f2h(W[((size_t)m * CIN + c) * 7 + k]);
            }
            *(short8*)&g_wb[(size_t)idx * 8] = u.v;
        }
    }

    __shared__ float tile[64][65];
    int b  = blockIdx.y;
    int v0 = blockIdx.x * 64;
    int t  = threadIdx.x;
    int tv = t & 15;    // v4-group: v = v0 + tv*4 .. +3
    int tc = t >> 4;    // c = tc + 16*i
#pragma unroll
    for (int i = 0; i < 4; i++) {
        int c = tc + 16 * i;
        int v = v0 + tv * 4;
        const float* src = x + ((size_t)b * CIN + c) * VV + v;
        f32x4 f;
        if (v + 3 < VV) {
            f = *(const f32x4*)src;
        } else {
            f[0] = v + 0 < VV ? src[0] : 0.f;
            f[1] = v + 1 < VV ? src[1] : 0.f;
            f[2] = v + 2 < VV ? src[2] : 0.f;
            f[3] = v + 3 < VV ? src[3] : 0.f;
        }
        tile[c][tv * 4 + 0] = f[0];
        tile[c][tv * 4 + 1] = f[1];
        tile[c][tv * 4 + 2] = f[2];
        tile[c][tv * 4 + 3] = f[3];
    }
    __syncthreads();
    int c8  = t & 7;    // c = c8*8 .. +7
    int tvv = t >> 3;   // v = v0 + tvv + 32*i
#pragma unroll
    for (int i = 0; i < 2; i++) {
        int v = v0 + tvv + 32 * i;
        if (v < VV) {
            union { _Float16 h[8]; short8 s; } u;
#pragma unroll
            for (int j = 0; j < 8; j++)
                u.h[j] = (_Float16)tile[c8 * 8 + j][tvv + 32 * i];
            *(short8*)(g_xt + ((size_t)b * VV + v) * CIN + c8 * 8) = u.s;
        }
    }
}

__device__ inline void feats(float f0, float f1, float f2, float f3, float* g) {
    g[0] = f0;
    g[1] = f1 + f2 + f3;
    float p12 = f1 * f2, p13 = f1 * f3, p23 = f2 * f3;
    g[2] = p12 * f3;
    g[3] = p12 + p13 + p23;
    g[4] = f1 * f1 + f2 * f2 + f3 * f3;
    g[5] = fabsf(f1 - f2) + fabsf(f1 - f3) + fabsf(f2 - f3);
    g[6] = f1 * f1 * f1 + f2 * f2 * f2 + f3 * f3 * f3;
}

// ---------------------------------------------------------------------------
// Main kernel, NV=16 occupancy build: LDS 14.6 KB -> 8 blocks/CU (wave-capped,
// 100% occupancy ceiling vs 62.5% at NV=32). The kernel is latency-bound with
// ~15% per-wave issue-readiness (measured: rounds 2/5/6/7 all ~70us across
// FETCH 77->50 MB and VALU 28->18%); doubling waves/SIMD is the lever.
// XCD-affine decode kept (measured FETCH 67->50 MB).
//  Phase 0: one coalesced wave-load: every wave loads all 16 slots' indices
//           (lane l -> slot=l>>2, j=l&3); thread (global slot s = t>>4)
//           reads its 4 indices from wave-local lanes 4s..4s+3.
//  Phase 1: gather: thread = (4 channels, 1 slot), 4 x 8B loads in flight;
//           feats for 4 channels; 7 x ds_write_b64 into G[16][PITCH].
//  Phase 2: 4 waves x (2m x 1n) mfma_f32_16x16x32_f16, A pipelined 1 kt.
//  Epilogue: nt stores. VV%16==0 -> no v guards.
// ---------------------------------------------------------------------------
__global__ __launch_bounds__(256, 8) void mesh_k(
        const void* __restrict__ Gi, const float* __restrict__ bias,
        float* __restrict__ out) {
    __shared__ _Float16 Gl[NV * PITCH];   // 14.6 KB

    int bid  = blockIdx.x;
    int b    = (bid & 7) >> 1;                 // XCD pair 2b, 2b+1
    int tile = ((bid >> 3) << 1) + (bid & 1);
    if (tile >= NTILES) return;                // block-uniform; before barriers
    int v0 = tile * NV;
    int t  = threadIdx.x;
    int w    = t >> 6;    // wave id
    int lane = t & 63;

    // Gi dtype sniff (int64 vs int32); wave-uniform.
    const unsigned* gu = (const unsigned*)Gi;
    bool is64 = ((gu[1] | gu[3] | gu[5] | gu[7]) == 0u);

    // ---- Phase 0: one coalesced wave-load of all 16x4 indices + shfl ----
    int val;
    {
        int vv = lane >> 2;         // slot 0..15 (every wave loads all 16)
        int j  = lane & 3;
        size_t gb = ((size_t)b * VV + v0 + vv) * 4 + j;
        long long xv = is64 ? ((const long long*)Gi)[gb]
                            : (long long)((const int*)Gi)[gb];
        val = (int)(xv < 0 ? 0 : (xv >= VV ? VV - 1 : xv));
    }

    // ---- W fragment prefetch for kt=0 (in flight during gather/feats) ----
    const half8* wbp = (const half8*)g_wb;
    half8 a0c = wbp[(2 * w    ) * 64 + lane];
    half8 a1c = wbp[(2 * w + 1) * 64 + lane];

    // ---- Phase 1: batched gather + features ----
    int c4   = t & 15;   // channels 4*c4 .. 4*c4+3
    int slot = t >> 4;   // GLOBAL vertex slot 0..15 (= 4w + (lane>>4))

    // slot s's indices live at wave-local lanes 4s..4s+3 (s<=15 -> lane<=63)
    int J[4];
    int srcl = slot << 2;
#pragma unroll
    for (int j = 0; j < 4; ++j) J[j] = __shfl(val, srcl + j, 64);

    const _Float16* base = g_xt + (size_t)b * VV * CIN + c4 * 4;
    half4 F[4];
#pragma unroll
    for (int j = 0; j < 4; ++j)
        F[j] = *(const half4*)(base + (size_t)J[j] * CIN);

    union { _Float16 h[4]; half4 v; } u[7];
#pragma unroll
    for (int i = 0; i < 4; ++i) {
        float g7[7];
        feats((float)F[0][i], (float)F[1][i], (float)F[2][i], (float)F[3][i], g7);
#pragma unroll
        for (int k = 0; k < 7; ++k) u[k].h[i] = (_Float16)g7[k];
    }
    _Float16* grow = &Gl[slot * PITCH + c4 * 4];   // feature k at elem k*64
#pragma unroll
    for (int k = 0; k < 7; ++k)
        *(half4*)(grow + k * 64) = u[k].v;         // ds_write_b64
    __syncthreads();

    // ---- Phase 2: MFMA, A-loads pipelined one kt ahead ----
    int l15  = lane & 15;
    int q    = lane >> 4;

    f32x4 acc[2] = {};
    half8 a0n, a1n;
#pragma unroll
    for (int kt = 0; kt < KT; ++kt) {
        if (kt + 1 < KT) {
            a0n = wbp[((kt + 1) * 8 + 2 * w    ) * 64 + lane];
            a1n = wbp[((kt + 1) * 8 + 2 * w + 1) * 64 + lane];
        }
        half8 b0 = *(const half8*)&Gl[l15 * PITCH + kt * 32 + q * 8];
        acc[0] = __builtin_amdgcn_mfma_f32_16x16x32_f16(a0c, b0, acc[0], 0, 0, 0);
        acc[1] = __builtin_amdgcn_mfma_f32_16x16x32_f16(a1c, b0, acc[1], 0, 0, 0);
        a0c = a0n; a1c = a1n;
    }

    // ---- Epilogue: D col=lane&15 (v), row=(lane>>4)*4+reg (o); nt stores ----
    int v = v0 + l15;   // always < VV (VV%16==0, tile guarded)
#pragma unroll
    for (int mt = 0; mt < 2; ++mt) {
        int o = 32 * w + mt * 16 + q * 4;
        float* po = out + ((size_t)b * COUT + o) * VV + v;
#pragma unroll
        for (int r = 0; r < 4; ++r)
            __builtin_nontemporal_store(acc[mt][r] + bias[o + r], po + (size_t)r * VV);
    }
}

// ---------------------------------------------------------------------------
extern "C" void kernel_launch(void* const* d_in, const int* in_sizes, int n_in,
                              void* d_out, int out_size, void* d_ws, size_t ws_size,
                              hipStream_t stream) {
    const float* x    = (const float*)d_in[0];
    const void*  Gi   = d_in[1];
    const float* W    = (const float*)d_in[2];
    const float* bias = (const float*)d_in[3];
    float* out        = (float*)d_out;

    dim3 gt((VV + 63) / 64, BB);
    transpose_k<<<gt, 256, 0, stream>>>(x, W);
    // 8 * 1563 blocks: (bid&7) selects the XCD-affine (batch, tile-parity) pair
    mesh_k<<<dim3(8 * ((NTILES + 1) / 2)), 256, 0, stream>>>(Gi, bias, out);
}

// Round 11
// 206.035 us; speedup vs baseline: 1.0691x; 1.0691x over previous
//
#include <hip/hip_runtime.h>
#include <cstdint>
#include <cstddef>

#define BB   4
#define CIN  64
#define VV   50000
#define COUT 128
#define NV   32            // vertices per tile
#define TPB  8             // tiles per block
#define NTILES 1563        // ceil(VV/NV)
#define NGRP 196           // ceil(NTILES/TPB)
#define KTOT 448           // CIN*7, kk = k*64 + c
#define KT   14            // KTOT/32 MFMA k-steps
#define PITCH 456          // G LDS row pitch in fp16 elems (448+8)

typedef __attribute__((ext_vector_type(8))) short     short8;
typedef __attribute__((ext_vector_type(8))) _Float16  half8;
typedef __attribute__((ext_vector_type(4))) float     f32x4;

// Static device buffers (no ws_size dependence). Rewritten every launch.
__device__ _Float16       g_xt[(size_t)BB * VV * CIN];   // x transposed [b][v][c], fp16, 25.6 MB
__device__ unsigned short g_wb[KT * 8 * 64 * 8];         // W in MFMA A-frag order (fp16 bits), 114 KB

__device__ inline unsigned short f2h(float f) {
    union { _Float16 h; unsigned short u; } cv;
    cv.h = (_Float16)f;
    return cv.u;
}

// ---------------------------------------------------------------------------
// Transpose x[B][C][V] (fp32) -> g_xt[B][V][C] (fp16), with the W pack fused
// into the first 28 blocks of batch 0. (Proven; unchanged.)
// ---------------------------------------------------------------------------
__global__ __launch_bounds__(256) void transpose_k(const float* __restrict__ x,
                                                   const float* __restrict__ W) {
    if (blockIdx.y == 0 && blockIdx.x < (KT * 8 * 64 + 255) / 256) {
        int idx = blockIdx.x * 256 + threadIdx.x;   // over KT*8*64 = 7168
        if (idx < KT * 8 * 64) {
            int lane = idx & 63;
            int mt   = (idx >> 6) & 7;
            int kt   = idx >> 9;
            int m    = mt * 16 + (lane & 15);
            int kb   = kt * 32 + (lane >> 4) * 8;
            union { unsigned short s[8]; short8 v; } u;
#pragma unroll
            for (int j = 0; j < 8; j++) {
                int kk = kb + j;
                int c  = kk & 63;
                int k  = kk >> 6;
                u.s[j] = f2h(W[((size_t)m * CIN + c) * 7 + k]);
            }
            *(short8*)&g_wb[(size_t)idx * 8] = u.v;
        }
    }

    __shared__ float tile[64][65];
    int b  = blockIdx.y;
    int v0 = blockIdx.x * 64;
    int t  = threadIdx.x;
    int tv = t & 15;    // v4-group: v = v0 + tv*4 .. +3
    int tc = t >> 4;    // c = tc + 16*i
#pragma unroll
    for (int i = 0; i < 4; i++) {
        int c = tc + 16 * i;
        int v = v0 + tv * 4;
        const float* src = x + ((size_t)b * CIN + c) * VV + v;
        f32x4 f;
        if (v + 3 < VV) {
            f = *(const f32x4*)src;
        } else {
            f[0] = v + 0 < VV ? src[0] : 0.f;
            f[1] = v + 1 < VV ? src[1] : 0.f;
            f[2] = v + 2 < VV ? src[2] : 0.f;
            f[3] = v + 3 < VV ? src[3] : 0.f;
        }
        tile[c][tv * 4 + 0] = f[0];
        tile[c][tv * 4 + 1] = f[1];
        tile[c][tv * 4 + 2] = f[2];
        tile[c][tv * 4 + 3] = f[3];
    }
    __syncthreads();
    int c8  = t & 7;    // c = c8*8 .. +7
    int tvv = t >> 3;   // v = v0 + tvv + 32*i
#pragma unroll
    for (int i = 0; i < 2; i++) {
        int v = v0 + tvv + 32 * i;
        if (v < VV) {
            union { _Float16 h[8]; short8 s; } u;
#pragma unroll
            for (int j = 0; j < 8; j++)
                u.h[j] = (_Float16)tile[c8 * 8 + j][tvv + 32 * i];
            *(short8*)(g_xt + ((size_t)b * VV + v) * CIN + c8 * 8) = u.s;
        }
    }
}

__device__ inline void feats(float f0, float f1, float f2, float f3, float* g) {
    g[0] = f0;
    g[1] = f1 + f2 + f3;
    float p12 = f1 * f2, p13 = f1 * f3, p23 = f2 * f3;
    g[2] = p12 * f3;
    g[3] = p12 + p13 + p23;
    g[4] = f1 * f1 + f2 * f2 + f3 * f3;
    g[5] = fabsf(f1 - f2) + fabsf(f1 - f3) + fabsf(f2 - f3);
    g[6] = f1 * f1 * f1 + f2 * f2 * f2 + f3 * f3 * f3;
}

// ---------------------------------------------------------------------------
// Main kernel: 8 tiles per block, A-fragments in REGISTERS (loaded once per
// block: kills the dominant L2 A-stream — 112KB/block was ~1792 lines/block,
// 6x the gather's line count; NV=16's 2x-blocks regression (+19us) matches
// this model quantitatively). G double-buffered in LDS; per tile:
//   feats(tau) -> ds_write G[tau&1] -> issue Gi(tau+2) -> barrier ->
//   issue gather(tau+1) -> MFMA(G[tau&1], A-regs) -> nt stores(tau).
// Gathers are issued BEFORE stores (vmcnt decrements in issue order, so the
// next tile's gather wait does not drain the 16 outstanding nt stores).
// One barrier per tile (separates all reads of buf from its next write).
// XCD-affine decode kept (measured FETCH 67->50 MB).
// ---------------------------------------------------------------------------
__global__ __launch_bounds__(256, 2) void mesh_k(
        const void* __restrict__ Gi, const float* __restrict__ bias,
        float* __restrict__ out) {
    __shared__ _Float16 Gl[2][NV * PITCH];   // 58.4 KB (double-buffered G)

    int bid  = blockIdx.x;
    int b    = (bid & 7) >> 1;                    // XCD pair 2b, 2b+1
    int grp  = ((bid >> 3) << 1) + (bid & 1);     // tile group 0..195
    int tile0 = grp * TPB;                        // always even, < NTILES
    int t = threadIdx.x;
    int w = t >> 6, lane = t & 63;

    // Gi dtype sniff (int64 vs int32); wave-uniform.
    const unsigned* gu = (const unsigned*)Gi;
    bool is64 = ((gu[1] | gu[3] | gu[5] | gu[7]) == 0u);
    const long long* g64 = (const long long*)Gi;
    const int*       g32 = (const int*)Gi;

    // ---- A fragments in registers: 28 x half8, loaded once per block ----
    const half8* wbp = (const half8*)g_wb;
    half8 A0[KT], A1[KT];
#pragma unroll
    for (int kt = 0; kt < KT; ++kt) {
        A0[kt] = wbp[(kt * 8 + 2 * w    ) * 64 + lane];
        A1[kt] = wbp[(kt * 8 + 2 * w + 1) * 64 + lane];
    }

    int c8   = t & 7;    // gather role: channels 8*c8..8*c8+7
    int slot = t >> 3;   // gather role: vertex slot 0..31
    int l15  = lane & 15, q = lane >> 4;
    int srcl = (lane >> 3) << 2;                  // wave-local idx source lane
    const _Float16* xb = g_xt + (size_t)b * VV * CIN + c8 * 8;

    int gvv = 8 * w + (lane >> 2), gj = lane & 3; // Gi-loader role (lanes<32)

    // wave-coalesced Gi load for this wave's 8 slots of tile ti (lanes 0..31)
    auto load_gi = [&](int ti) -> int {
        int v = ti * NV + gvv;
        if (v >= VV) v = VV - 1;                  // tail: valid mem, garbage ok
        size_t gb = ((size_t)b * VV + v) * 4 + gj;
        long long xv = is64 ? g64[gb] : (long long)g32[gb];
        return (int)(xv < 0 ? 0 : (xv >= VV ? VV - 1 : xv));
    };
    auto issue_gather = [&](half8* F, int val) {
        int J[4];
#pragma unroll
        for (int j = 0; j < 4; ++j) J[j] = __shfl(val, srcl + j, 64);
#pragma unroll
        for (int j = 0; j < 4; ++j)
            F[j] = *(const half8*)(xb + (size_t)J[j] * CIN);
    };

    // bias per wave-row, loaded once
    float bs[2][4];
#pragma unroll
    for (int mt = 0; mt < 2; ++mt)
#pragma unroll
        for (int r = 0; r < 4; ++r)
            bs[mt][r] = bias[32 * w + mt * 16 + q * 4 + r];

    // ---- pipeline prologue: Gi(0), gather(0), Gi(1) ----
    int valA = 0, valB = 0;
    half8 Fa[4], Fb[4];
    if (lane < 32) valA = load_gi(tile0);
    issue_gather(Fa, valA);
    if (lane < 32) valB = load_gi(tile0 + 1);     // grp 195 still has >=3 tiles

#pragma unroll
    for (int tau = 0; tau < TPB; ++tau) {
        int tile = tile0 + tau;
        if (tile >= NTILES) break;                // block-uniform
        int v0 = tile * NV;
        bool hasN1 = (tau + 1 < TPB) && (tile + 1 < NTILES);
        bool hasN2 = (tau + 2 < TPB) && (tile + 2 < NTILES);

        half8* Fc = (tau & 1) ? Fb : Fa;          // tau constant after unroll
        half8* Fn = (tau & 1) ? Fa : Fb;
        int   valN = (tau & 1) ? valA : valB;     // val for tile tau+1

        // feats for 8 channels (waits on gather(tau) only)
        union { _Float16 h[8]; short8 s; } u[7];
#pragma unroll
        for (int i = 0; i < 8; ++i) {
            float g7[7];
            feats((float)Fc[0][i], (float)Fc[1][i], (float)Fc[2][i],
                  (float)Fc[3][i], g7);
#pragma unroll
            for (int k = 0; k < 7; ++k) u[k].h[i] = (_Float16)g7[k];
        }
        _Float16* grow = &Gl[tau & 1][slot * PITCH + c8 * 8];
#pragma unroll
        for (int k = 0; k < 7; ++k)
            *(short8*)(grow + k * 64) = u[k].s;   // ds_write_b128

        // issue Gi(tau+2) into the freed val slot (tile parity == tau parity)
        if (hasN2 && lane < 32) {
            if (tau & 1) valB = load_gi(tile + 2);
            else         valA = load_gi(tile + 2);
        }

        __syncthreads();   // G[tau&1] ready; also fences buf reuse (see hdr)

        // issue gather(tau+1) BEFORE MFMA and BEFORE stores
        if (hasN1) issue_gather(Fn, valN);

        // ---- MFMA from LDS B + register A (no global loads here) ----
        f32x4 acc[2][2] = {};
        const _Float16* gb0 = &Gl[tau & 1][(l15     ) * PITCH];
        const _Float16* gb1 = &Gl[tau & 1][(l15 + 16) * PITCH];
#pragma unroll
        for (int kt = 0; kt < KT; ++kt) {
            half8 b0 = *(const half8*)(gb0 + kt * 32 + q * 8);
            half8 b1 = *(const half8*)(gb1 + kt * 32 + q * 8);
            acc[0][0] = __builtin_amdgcn_mfma_f32_16x16x32_f16(A0[kt], b0, acc[0][0], 0, 0, 0);
            acc[0][1] = __builtin_amdgcn_mfma_f32_16x16x32_f16(A0[kt], b1, acc[0][1], 0, 0, 0);
            acc[1][0] = __builtin_amdgcn_mfma_f32_16x16x32_f16(A1[kt], b0, acc[1][0], 0, 0, 0);
            acc[1][1] = __builtin_amdgcn_mfma_f32_16x16x32_f16(A1[kt], b1, acc[1][1], 0, 0, 0);
        }

        // ---- epilogue: D col=lane&15 (v), row=(lane>>4)*4+reg (o) ----
#pragma unroll
        for (int mt = 0; mt < 2; ++mt) {
            int o = 32 * w + mt * 16 + q * 4;
#pragma unroll
            for (int n = 0; n < 2; ++n) {
                int vv = v0 + n * 16 + l15;
                if (vv < VV) {
                    float* po = out + ((size_t)b * COUT + o) * VV + vv;
#pragma unroll
                    for (int r = 0; r < 4; ++r)
                        __builtin_nontemporal_store(acc[mt][n][r] + bs[mt][r],
                                                    po + (size_t)r * VV);
                }
            }
        }
    }
}

// ---------------------------------------------------------------------------
extern "C" void kernel_launch(void* const* d_in, const int* in_sizes, int n_in,
                              void* d_out, int out_size, void* d_ws, size_t ws_size,
                              hipStream_t stream) {
    const float* x    = (const float*)d_in[0];
    const void*  Gi   = d_in[1];
    const float* W    = (const float*)d_in[2];
    const float* bias = (const float*)d_in[3];
    float* out        = (float*)d_out;

    dim3 gt((VV + 63) / 64, BB);
    transpose_k<<<gt, 256, 0, stream>>>(x, W);
    // 8 * 98 = 784 blocks: (bid&7) -> XCD-affine (batch, group-parity)
    mesh_k<<<dim3(8 * (NGRP / 2)), 256, 0, stream>>>(Gi, bias, out);
}